// Round 1
// baseline (1092.544 us; speedup 1.0000x reference)
//
#include <hip/hip_runtime.h>
#include <cfloat>

#define N_Q     65536
#define D_DIM   256
#define K_CODES 1024

// output float offsets (tuple concatenated flat, all as float32)
#define OUT_QST   0
#define OUT_LOSS  16777216
#define OUT_IDX   16777217
#define OUT_EMBED 16842753
#define OUT_COUNT 17104897
#define OUT_EMAW  17105921

// workspace byte offsets
#define WS_IDX   0u          // 65536 * 4  (int32 argmin)
#define WS_CNT   262144u     // 1024 * 4   (counts, zeroed)
#define WS_DW    266240u     // 262144 * 4 (dw scatter, zeroed)
#define WS_LOSS  1314816u    // 8          (double loss accum, zeroed)
#define WS_CS    1314880u    // 1024 * 4   (laplace-smoothed counts)
#define WS_ZZ    1318976u    // 65536 * 4  (per-query ||z||^2)
#define WS_EN    1581120u    // 1024 * 4   (per-code ||e||^2)

// ---------------------------------------------------------------------------
// row-wise sum of squares for a [rows, 256] matrix; one wave per row
__global__ void rownorm2_kernel(const float* __restrict__ x, float* __restrict__ out)
{
    int wave = threadIdx.x >> 6, lane = threadIdx.x & 63;
    int row  = blockIdx.x * 4 + wave;
    const float4 v = *(const float4*)&x[(size_t)row * D_DIM + lane * 4];
    float s = v.x * v.x + v.y * v.y + v.z * v.z + v.w * v.w;
    #pragma unroll
    for (int m = 32; m >= 1; m >>= 1) s += __shfl_down(s, m, 64);
    if (lane == 0) out[row] = s;
}

// ---------------------------------------------------------------------------
// fused distance + argmin. Block: 128 queries x 128-code chunks, D chunked by 32.
// Thread (tx = t&15 codes-group, ty = t>>4 query-group): 8 queries x 8 codes tile.
// Score replicates np op order: fl(fl(zz - fl(2*dot)) + e_norm); ties -> lowest idx.
#define MQ   128
#define KC   128
#define DK   32
#define LSTR 36   // +4 pad: all LDS read conflicts <= 2-way (free), float4-aligned

__launch_bounds__(256, 2)
__global__ void argmin_kernel(const float* __restrict__ z,
                              const float* __restrict__ embed,
                              const float* __restrict__ enorm,
                              const float* __restrict__ zz,
                              int* __restrict__ idx_i,
                              float* __restrict__ idx_f)
{
    __shared__ float Zs[MQ * LSTR];
    __shared__ float Es[KC * LSTR];
    const int t  = threadIdx.x;
    const int tx = t & 15, ty = t >> 4;
    const int qbase = blockIdx.x * MQ;

    float aq[8];
    #pragma unroll
    for (int j = 0; j < 8; ++j) aq[j] = zz[qbase + ty + 16 * j];

    float rv[8];
    int   rc[8];
    #pragma unroll
    for (int j = 0; j < 8; ++j) { rv[j] = FLT_MAX; rc[j] = 0x7fffffff; }

    for (int kc = 0; kc < K_CODES / KC; ++kc) {
        float acc[8][8];
        #pragma unroll
        for (int j = 0; j < 8; ++j)
            #pragma unroll
            for (int i = 0; i < 8; ++i) acc[j][i] = 0.f;

        for (int dk = 0; dk < D_DIM / DK; ++dk) {
            __syncthreads();
            // stage Z tile: 128 rows x 32 floats, float4 coalesced
            #pragma unroll
            for (int r = 0; r < 4; ++r) {
                int lin = r * 256 + t;
                int row = lin >> 3, f4 = lin & 7;
                *(float4*)&Zs[row * LSTR + f4 * 4] =
                    *(const float4*)&z[(size_t)(qbase + row) * D_DIM + dk * DK + f4 * 4];
            }
            // stage E tile
            #pragma unroll
            for (int r = 0; r < 4; ++r) {
                int lin = r * 256 + t;
                int row = lin >> 3, f4 = lin & 7;
                *(float4*)&Es[row * LSTR + f4 * 4] =
                    *(const float4*)&embed[(size_t)(kc * KC + row) * D_DIM + dk * DK + f4 * 4];
            }
            __syncthreads();
            #pragma unroll
            for (int d = 0; d < DK; ++d) {
                float zf[8], ef[8];
                #pragma unroll
                for (int j = 0; j < 8; ++j) zf[j] = Zs[(ty + 16 * j) * LSTR + d];
                #pragma unroll
                for (int i = 0; i < 8; ++i) ef[i] = Es[(tx + 16 * i) * LSTR + d];
                #pragma unroll
                for (int j = 0; j < 8; ++j)
                    #pragma unroll
                    for (int i = 0; i < 8; ++i)
                        acc[j][i] += zf[j] * ef[i];
            }
        }
        // epilogue for this 128-code chunk
        float en[8];
        #pragma unroll
        for (int i = 0; i < 8; ++i) en[i] = enorm[kc * KC + tx + 16 * i];
        #pragma unroll
        for (int j = 0; j < 8; ++j) {
            float bv = FLT_MAX;
            int   bc = 0x7fffffff;
            #pragma unroll
            for (int i = 0; i < 8; ++i) {
                float b  = 2.0f * acc[j][i];   // exact (x2)
                float t1 = aq[j] - b;          // fp32 round at |zz| scale (matches np)
                float s  = t1 + en[i];         // fp32 round again (matches np)
                int   c  = kc * KC + tx + 16 * i;
                if (s < bv) { bv = s; bc = c; }  // i ascending -> c ascending: first-idx tie
            }
            // reduce across the 16 tx lanes sharing this query (lanes l..l+15)
            #pragma unroll
            for (int m = 1; m < 16; m <<= 1) {
                float ov = __shfl_xor(bv, m, 64);
                int   oc = __shfl_xor(bc, m, 64);
                if (ov < bv || (ov == bv && oc < bc)) { bv = ov; bc = oc; }
            }
            if (bv < rv[j] || (bv == rv[j] && bc < rc[j])) { rv[j] = bv; rc[j] = bc; }
        }
    }
    if (tx == 0) {
        #pragma unroll
        for (int j = 0; j < 8; ++j) {
            int n = qbase + ty + 16 * j;
            idx_i[n] = rc[j];
            idx_f[n] = (float)rc[j];
        }
    }
}

// ---------------------------------------------------------------------------
// gather q = embed[idx], write q_st = z + (q - z) (literal op order), accumulate
// sum((z-q)^2) into a double scalar
__global__ void qst_loss_kernel(const float* __restrict__ z,
                                const float* __restrict__ embed,
                                const int* __restrict__ idx,
                                float* __restrict__ qst,
                                double* __restrict__ loss)
{
    int tid = blockIdx.x * blockDim.x + threadIdx.x;
    int e0  = tid * 4;
    int n   = e0 >> 8, d = e0 & 255;
    int k   = idx[n];
    const float4 q4 = *(const float4*)&embed[(size_t)k * D_DIM + d];
    const float4 z4 = *(const float4*)&z[e0];
    float4 o;
    o.x = z4.x + (q4.x - z4.x);
    o.y = z4.y + (q4.y - z4.y);
    o.z = z4.z + (q4.z - z4.z);
    o.w = z4.w + (q4.w - z4.w);
    *(float4*)&qst[e0] = o;
    float dx = z4.x - q4.x, dy = z4.y - q4.y, dz = z4.z - q4.z, dw = z4.w - q4.w;
    float s = dx * dx + dy * dy + dz * dz + dw * dw;
    #pragma unroll
    for (int m = 32; m >= 1; m >>= 1) s += __shfl_down(s, m, 64);
    __shared__ float ps[4];
    int wave = threadIdx.x >> 6, lane = threadIdx.x & 63;
    if (lane == 0) ps[wave] = s;
    __syncthreads();
    if (threadIdx.x == 0)
        atomicAdd(loss, (double)((ps[0] + ps[1]) + (ps[2] + ps[3])));
}

// ---------------------------------------------------------------------------
// counts[k] += 1, dw[k,:] += z[n,:]  (one wave per query; fp32 atomics)
__global__ void scatter_kernel(const float* __restrict__ z,
                               const int* __restrict__ idx,
                               float* __restrict__ cnt,
                               float* __restrict__ dw)
{
    int wave = threadIdx.x >> 6, lane = threadIdx.x & 63;
    int n = blockIdx.x * 4 + wave;
    int k = idx[n];
    const float4 v = *(const float4*)&z[(size_t)n * D_DIM + lane * 4];
    float* dst = &dw[(size_t)k * D_DIM + lane * 4];
    atomicAdd(dst + 0, v.x);
    atomicAdd(dst + 1, v.y);
    atomicAdd(dst + 2, v.z);
    atomicAdd(dst + 3, v.w);
    if (lane == 0) atomicAdd(&cnt[k], 1.0f);
}

// ---------------------------------------------------------------------------
// new_count, n = sum(new_count), cs, vq_loss finalize (single block of 1024)
__global__ void fin_counts_kernel(const float* __restrict__ ema_count,
                                  const float* __restrict__ cnt,
                                  const double* __restrict__ loss,
                                  float* __restrict__ out_count,
                                  float* __restrict__ out_loss,
                                  float* __restrict__ cs)
{
    __shared__ float red[1024];
    int t = threadIdx.x;
    float c = 0.99f * ema_count[t] + 0.01f * cnt[t];
    out_count[t] = c;
    red[t] = c;
    __syncthreads();
    for (int s = 512; s >= 1; s >>= 1) {
        if (t < s) red[t] += red[t + s];
        __syncthreads();
    }
    float n = red[0];
    cs[t] = (c + 1e-5f) / (n + 1024.0f * 1e-5f) * n;
    if (t == 0) {
        float m = (float)(loss[0] / (double)((size_t)N_Q * D_DIM));
        out_loss[0] = m + 0.25f * m;   // codebook + BETA*commit, bitwise equal halves
    }
}

// ---------------------------------------------------------------------------
// new_ema_w = 0.99*ema_w + 0.01*dw ; new_embed = new_ema_w / cs[row]
// (scalar stores: out regions start at odd float offsets)
__global__ void fin_embed_kernel(const float* __restrict__ ema_w,
                                 const float* __restrict__ dw,
                                 const float* __restrict__ cs,
                                 float* __restrict__ out_embed,
                                 float* __restrict__ out_emaw)
{
    int tid = blockIdx.x * blockDim.x + threadIdx.x;
    int e0  = tid * 4;
    float c = cs[e0 >> 8];
    #pragma unroll
    for (int k = 0; k < 4; ++k) {
        float w = 0.99f * ema_w[e0 + k] + 0.01f * dw[e0 + k];
        out_emaw[e0 + k]  = w;
        out_embed[e0 + k] = w / c;
    }
}

// ---------------------------------------------------------------------------
extern "C" void kernel_launch(void* const* d_in, const int* in_sizes, int n_in,
                              void* d_out, int out_size, void* d_ws, size_t ws_size,
                              hipStream_t stream)
{
    const float* z          = (const float*)d_in[0];
    const float* embed      = (const float*)d_in[1];
    const float* ema_count  = (const float*)d_in[2];
    const float* ema_weight = (const float*)d_in[3];
    float* out = (float*)d_out;
    char*  ws  = (char*)d_ws;

    int*    ws_idx  = (int*)(ws + WS_IDX);
    float*  ws_cnt  = (float*)(ws + WS_CNT);
    float*  ws_dw   = (float*)(ws + WS_DW);
    double* ws_loss = (double*)(ws + WS_LOSS);
    float*  ws_cs   = (float*)(ws + WS_CS);
    float*  ws_zz   = (float*)(ws + WS_ZZ);
    float*  ws_en   = (float*)(ws + WS_EN);

    // zero the accumulators (counts, dw, loss) in one shot
    hipMemsetAsync(ws + WS_CNT, 0, WS_LOSS + 8 - WS_CNT, stream);

    rownorm2_kernel<<<K_CODES / 4, 256, 0, stream>>>(embed, ws_en);
    rownorm2_kernel<<<N_Q / 4,     256, 0, stream>>>(z, ws_zz);
    argmin_kernel<<<N_Q / MQ, 256, 0, stream>>>(z, embed, ws_en, ws_zz,
                                                ws_idx, out + OUT_IDX);
    qst_loss_kernel<<<(N_Q * (D_DIM / 4)) / 256, 256, 0, stream>>>(
        z, embed, ws_idx, out + OUT_QST, ws_loss);
    scatter_kernel<<<N_Q / 4, 256, 0, stream>>>(z, ws_idx, ws_cnt, ws_dw);
    fin_counts_kernel<<<1, 1024, 0, stream>>>(ema_count, ws_cnt, ws_loss,
                                              out + OUT_COUNT, out + OUT_LOSS, ws_cs);
    fin_embed_kernel<<<(K_CODES * (D_DIM / 4)) / 256, 256, 0, stream>>>(
        ema_weight, ws_dw, ws_cs, out + OUT_EMBED, out + OUT_EMAW);
}